// Round 1
// baseline (2097.529 us; speedup 1.0000x reference)
//
#include <hip/hip_runtime.h>

#define NN 50000
#define NE 600000
#define NG 64

// ---------------- degree / normalization ----------------
__global__ void k_init_dinv(float* __restrict__ dinv) {
    int i = blockIdx.x * blockDim.x + threadIdx.x;
    if (i < NN) dinv[i] = 1.0f;  // self-loop contribution
}

__global__ void k_deg(const int* __restrict__ dst, float* __restrict__ dinv) {
    int e = blockIdx.x * blockDim.x + threadIdx.x;
    if (e < NE) unsafeAtomicAdd(&dinv[dst[e]], 1.0f);
}

__global__ void k_fin_dinv(float* __restrict__ dinv) {
    int i = blockIdx.x * blockDim.x + threadIdx.x;
    if (i < NN) dinv[i] = rsqrtf(fmaxf(dinv[i], 1.0f));
}

// ---------------- dense GEMM: H[M,COUT] = X[M,CIN] @ W[CIN,COUT] ----------------
template <int CIN, int COUT>
__global__ __launch_bounds__(256) void k_gemm(const float* __restrict__ X,
                                              const float* __restrict__ W,
                                              float* __restrict__ H) {
    constexpr int TPR = COUT / 4;      // threads per row
    constexpr int RPB = 256 / TPR;     // rows per block
    constexpr int F4R = CIN / 4;
    __shared__ float xs[RPB][CIN + 4];
    const int tid = threadIdx.x;
    const long row0 = (long)blockIdx.x * RPB;

    for (int idx = tid; idx < RPB * F4R; idx += 256) {
        int r = idx / F4R, c4 = idx % F4R;
        long row = row0 + r;
        float4 v = make_float4(0.f, 0.f, 0.f, 0.f);
        if (row < NN) v = ((const float4*)X)[row * F4R + c4];
        xs[r][c4 * 4 + 0] = v.x; xs[r][c4 * 4 + 1] = v.y;
        xs[r][c4 * 4 + 2] = v.z; xs[r][c4 * 4 + 3] = v.w;
    }
    __syncthreads();

    const int r = tid / TPR;
    const int j = (tid % TPR) * 4;
    const long row = row0 + r;
    if (row >= NN) return;

    float4 acc = make_float4(0.f, 0.f, 0.f, 0.f);
#pragma unroll 8
    for (int k = 0; k < CIN; ++k) {
        float xv = xs[r][k];
        float4 w = *(const float4*)&W[k * COUT + j];
        acc.x += xv * w.x; acc.y += xv * w.y;
        acc.z += xv * w.z; acc.w += xv * w.w;
    }
    *(float4*)&H[row * COUT + j] = acc;
}

// ---------------- aggregation init with self-loop term: AGG = H * dinv^2 ----------------
template <int C>
__global__ void k_selfinit(const float* __restrict__ H, const float* __restrict__ dinv,
                           float* __restrict__ AGG) {
    constexpr int F4 = C / 4;
    long idx = (long)blockIdx.x * blockDim.x + threadIdx.x;  // float4 index
    if (idx >= (long)NN * F4) return;
    long node = idx / F4;
    float w = dinv[node];
    w = w * w;
    float4 v = ((const float4*)H)[idx];
    v.x *= w; v.y *= w; v.z *= w; v.w *= w;
    ((float4*)AGG)[idx] = v;
}

// ---------------- per-edge scatter-add: AGG[dst] += H[src] * dinv[s]*dinv[d] ----------------
template <int C>
__global__ __launch_bounds__(256) void k_edgeagg(const int* __restrict__ src,
                                                 const int* __restrict__ dst,
                                                 const float* __restrict__ dinv,
                                                 const float* __restrict__ H,
                                                 float* __restrict__ AGG) {
    constexpr int TPE = C / 4;  // threads per edge
    int tid = blockIdx.x * blockDim.x + threadIdx.x;
    int e = tid / TPE;
    if (e >= NE) return;
    int c = (tid % TPE) * 4;
    int s = src[e], d = dst[e];
    float norm = dinv[s] * dinv[d];
    float4 v = *(const float4*)&H[(long)s * C + c];
    float* p = &AGG[(long)d * C + c];
    unsafeAtomicAdd(p + 0, v.x * norm);
    unsafeAtomicAdd(p + 1, v.y * norm);
    unsafeAtomicAdd(p + 2, v.z * norm);
    unsafeAtomicAdd(p + 3, v.w * norm);
}

// ---------------- bias + relu (C=128), in place ----------------
__global__ void k_biasrelu(float* __restrict__ A, const float* __restrict__ b) {
    long idx = (long)blockIdx.x * blockDim.x + threadIdx.x;  // float4 index over NN*128
    if (idx >= (long)NN * 32) return;
    int c4 = (int)(idx & 31) * 4;
    float4 v = ((float4*)A)[idx];
    float4 bb = *(const float4*)&b[c4];
    v.x = fmaxf(v.x + bb.x, 0.f);
    v.y = fmaxf(v.y + bb.y, 0.f);
    v.z = fmaxf(v.z + bb.z, 0.f);
    v.w = fmaxf(v.w + bb.w, 0.f);
    ((float4*)A)[idx] = v;
}

// ---------------- pooling ----------------
__global__ void k_zeropool(float* __restrict__ p) {
    int i = blockIdx.x * blockDim.x + threadIdx.x;
    if (i < NG * 64 + NG) p[i] = 0.f;
}

__global__ void k_pool(const float* __restrict__ H, const int* __restrict__ batch,
                       float* __restrict__ psum, float* __restrict__ pcnt) {
    int idx = blockIdx.x * blockDim.x + threadIdx.x;  // 16 threads per node
    int node = idx >> 4;
    if (node >= NN) return;
    int c = (idx & 15) * 4;
    int g = batch[node];
    float4 v = *(const float4*)&H[(long)node * 64 + c];
    float* p = &psum[g * 64 + c];
    unsafeAtomicAdd(p + 0, v.x);
    unsafeAtomicAdd(p + 1, v.y);
    unsafeAtomicAdd(p + 2, v.z);
    unsafeAtomicAdd(p + 3, v.w);
    if (c == 0) unsafeAtomicAdd(&pcnt[g], 1.0f);
}

__global__ void k_final(const float* __restrict__ psum, const float* __restrict__ pcnt,
                        const float* __restrict__ b2, float* __restrict__ out) {
    int i = blockIdx.x * blockDim.x + threadIdx.x;
    if (i < NG * 64) {
        int g = i >> 6, c = i & 63;
        out[i] = psum[i] / fmaxf(pcnt[g], 1.0f) + b2[c];
    }
}

extern "C" void kernel_launch(void* const* d_in, const int* in_sizes, int n_in,
                              void* d_out, int out_size, void* d_ws, size_t ws_size,
                              hipStream_t stream) {
    const float* x  = (const float*)d_in[0];
    const float* W1 = (const float*)d_in[1];
    const float* b1 = (const float*)d_in[2];
    const float* W2 = (const float*)d_in[3];
    const float* b2 = (const float*)d_in[4];
    const int* ei   = (const int*)d_in[5];
    const int* src  = ei;
    const int* dst  = ei + NE;
    const int* batch = (const int*)d_in[6];
    float* out = (float*)d_out;

    float* ws   = (float*)d_ws;
    float* dinv = ws;                       // 50176 floats
    float* bufA = dinv + 50176;             // NN*128
    float* bufB = bufA + (long)NN * 128;    // NN*128
    float* psum = bufB + (long)NN * 128;    // 64*64
    float* pcnt = psum + NG * 64;           // 64

    // normalization coefficients
    k_init_dinv<<<(NN + 255) / 256, 256, 0, stream>>>(dinv);
    k_deg<<<(NE + 255) / 256, 256, 0, stream>>>(dst, dinv);
    k_fin_dinv<<<(NN + 255) / 256, 256, 0, stream>>>(dinv);

    // ---- layer 1: C=128 -> 128 ----
    k_gemm<128, 128><<<NN / 8, 256, 0, stream>>>(x, W1, bufA);          // bufA = x@W1
    k_selfinit<128><<<(NN * 32 + 255) / 256, 256, 0, stream>>>(bufA, dinv, bufB);
    k_edgeagg<128><<<(NE * 32 + 255) / 256, 256, 0, stream>>>(src, dst, dinv, bufA, bufB);
    k_biasrelu<<<(NN * 32 + 255) / 256, 256, 0, stream>>>(bufB, b1);    // bufB = relu(agg+b1)

    // ---- layer 2: C=128 -> 64 ----
    k_gemm<128, 64><<<NN / 16, 256, 0, stream>>>(bufB, W2, bufA);       // bufA = bufB@W2
    k_selfinit<64><<<(NN * 16 + 255) / 256, 256, 0, stream>>>(bufA, dinv, bufB);
    k_edgeagg<64><<<(NE * 16 + 255) / 256, 256, 0, stream>>>(src, dst, dinv, bufA, bufB);

    // ---- pooling (b2 folded into finalize) ----
    k_zeropool<<<(NG * 64 + NG + 255) / 256, 256, 0, stream>>>(psum);
    k_pool<<<(NN * 16 + 255) / 256, 256, 0, stream>>>(bufB, batch, psum, pcnt);
    k_final<<<(NG * 64 + 255) / 256, 256, 0, stream>>>(psum, pcnt, b2, out);
}

// Round 2
// 471.943 us; speedup vs baseline: 4.4445x; 4.4445x over previous
//
#include <hip/hip_runtime.h>

#define NN 50000
#define NE 600000
#define NG 64

// ---------------- degree histogram (int) ----------------
__global__ void k_zero_deg(int* __restrict__ deg) {
    int i = blockIdx.x * blockDim.x + threadIdx.x;
    if (i < NN) deg[i] = 0;
}

__global__ void k_hist(const int* __restrict__ dst, int* __restrict__ deg) {
    int e = blockIdx.x * blockDim.x + threadIdx.x;
    if (e < NE) atomicAdd(&deg[dst[e]], 1);
}

__global__ void k_dinv(const int* __restrict__ deg, float* __restrict__ dinv) {
    int i = blockIdx.x * blockDim.x + threadIdx.x;
    if (i < NN) dinv[i] = rsqrtf((float)(deg[i] + 1));  // +1 self-loop, always >=1
}

// ---------------- exclusive scan deg -> rowptr (single block) ----------------
__global__ __launch_bounds__(1024) void k_scan(const int* __restrict__ deg,
                                               int* __restrict__ rowptr,
                                               int* __restrict__ cursor) {
    __shared__ int sums[1024];
    const int T = 1024;
    const int CH = (NN + T - 1) / T;  // 49
    int t = threadIdx.x;
    int beg = t * CH;
    int end = beg + CH < NN ? beg + CH : NN;
    int s = 0;
    for (int i = beg; i < end; ++i) s += deg[i];
    sums[t] = s;
    __syncthreads();
    for (int off = 1; off < T; off <<= 1) {
        int v = sums[t];
        int u = (t >= off) ? sums[t - off] : 0;
        __syncthreads();
        sums[t] = v + u;
        __syncthreads();
    }
    int base = (t > 0) ? sums[t - 1] : 0;
    for (int i = beg; i < end; ++i) {
        rowptr[i] = base;
        cursor[i] = base;
        base += deg[i];
    }
    if (t == T - 1) rowptr[NN] = base;  // == NE
}

// ---------------- scatter edges into CSR buckets ----------------
__global__ void k_scatter(const int* __restrict__ src, const int* __restrict__ dst,
                          int* __restrict__ cursor, int* __restrict__ csr_src) {
    int e = blockIdx.x * blockDim.x + threadIdx.x;
    if (e >= NE) return;
    int d = dst[e];
    int p = atomicAdd(&cursor[d], 1);
    csr_src[p] = src[e];
}

// ---------------- dense GEMM: H[M,COUT] = X[M,CIN] @ W[CIN,COUT] ----------------
template <int CIN, int COUT>
__global__ __launch_bounds__(256) void k_gemm(const float* __restrict__ X,
                                              const float* __restrict__ W,
                                              float* __restrict__ H) {
    constexpr int TPR = COUT / 4;      // threads per row
    constexpr int RPB = 256 / TPR;     // rows per block
    constexpr int F4R = CIN / 4;
    __shared__ float xs[RPB][CIN + 4];
    const int tid = threadIdx.x;
    const long row0 = (long)blockIdx.x * RPB;

    for (int idx = tid; idx < RPB * F4R; idx += 256) {
        int r = idx / F4R, c4 = idx % F4R;
        long row = row0 + r;
        float4 v = make_float4(0.f, 0.f, 0.f, 0.f);
        if (row < NN) v = ((const float4*)X)[row * F4R + c4];
        xs[r][c4 * 4 + 0] = v.x; xs[r][c4 * 4 + 1] = v.y;
        xs[r][c4 * 4 + 2] = v.z; xs[r][c4 * 4 + 3] = v.w;
    }
    __syncthreads();

    const int r = tid / TPR;
    const int j = (tid % TPR) * 4;
    const long row = row0 + r;
    if (row >= NN) return;

    float4 acc = make_float4(0.f, 0.f, 0.f, 0.f);
#pragma unroll 8
    for (int k = 0; k < CIN; ++k) {
        float xv = xs[r][k];
        float4 w = *(const float4*)&W[k * COUT + j];
        acc.x += xv * w.x; acc.y += xv * w.y;
        acc.z += xv * w.z; acc.w += xv * w.w;
    }
    *(float4*)&H[row * COUT + j] = acc;
}

// ---------------- gather aggregation: OUT[d] = sum_in(H[s]*dinv[s])*dinv[d] + self ----------------
template <int C, bool BIAS_RELU>
__global__ __launch_bounds__(256) void k_agg(const int* __restrict__ rowptr,
                                             const int* __restrict__ csr_src,
                                             const float* __restrict__ dinv,
                                             const float* __restrict__ H,
                                             const float* __restrict__ bias,
                                             float* __restrict__ OUT) {
    constexpr int TPN = C / 4;        // threads per node (float4 channels)
    constexpr int NPB = 256 / TPN;    // nodes per block
    const int node = blockIdx.x * NPB + threadIdx.x / TPN;
    if (node >= NN) return;
    const int lane = threadIdx.x % TPN;
    const float dd = dinv[node];
    const float4* __restrict__ H4 = (const float4*)H;

    // self-loop term: H[node] * dinv[node]^2
    float4 v = H4[(long)node * TPN + lane];
    const float w = dd * dd;
    float4 acc = make_float4(v.x * w, v.y * w, v.z * w, v.w * w);

    const int beg = rowptr[node], end = rowptr[node + 1];
    for (int k = beg; k < end; ++k) {
        int s = csr_src[k];
        float nrm = dinv[s] * dd;
        float4 h = H4[(long)s * TPN + lane];
        acc.x += h.x * nrm; acc.y += h.y * nrm;
        acc.z += h.z * nrm; acc.w += h.w * nrm;
    }
    if (BIAS_RELU) {
        float4 bb = ((const float4*)bias)[lane];
        acc.x = fmaxf(acc.x + bb.x, 0.f);
        acc.y = fmaxf(acc.y + bb.y, 0.f);
        acc.z = fmaxf(acc.z + bb.z, 0.f);
        acc.w = fmaxf(acc.w + bb.w, 0.f);
    }
    ((float4*)OUT)[(long)node * TPN + lane] = acc;
}

// ---------------- per-graph mean pool (batch sorted, binary search) ----------------
__global__ __launch_bounds__(256) void k_pool(const float* __restrict__ H,
                                              const int* __restrict__ batch,
                                              const float* __restrict__ b2,
                                              float* __restrict__ out) {
    const int g = blockIdx.x;  // one block per graph
    // lower_bound(batch, key)
    int beg, end;
    {
        int lo = 0, hi = NN;
        while (lo < hi) { int mid = (lo + hi) >> 1; if (batch[mid] < g) lo = mid + 1; else hi = mid; }
        beg = lo;
        lo = beg; hi = NN;
        while (lo < hi) { int mid = (lo + hi) >> 1; if (batch[mid] < g + 1) lo = mid + 1; else hi = mid; }
        end = lo;
    }
    const int ch = threadIdx.x & 63;
    const int sub = threadIdx.x >> 6;  // 0..3
    float s = 0.f;
    for (int n = beg + sub; n < end; n += 4) s += H[(long)n * 64 + ch];
    __shared__ float red[4][64];
    red[sub][ch] = s;
    __syncthreads();
    if (sub == 0) {
        float tot = red[0][ch] + red[1][ch] + red[2][ch] + red[3][ch];
        int cnt = end - beg;
        out[g * 64 + ch] = (cnt > 0) ? (tot / (float)cnt + b2[ch]) : 0.f;
    }
}

extern "C" void kernel_launch(void* const* d_in, const int* in_sizes, int n_in,
                              void* d_out, int out_size, void* d_ws, size_t ws_size,
                              hipStream_t stream) {
    const float* x  = (const float*)d_in[0];
    const float* W1 = (const float*)d_in[1];
    const float* b1 = (const float*)d_in[2];
    const float* W2 = (const float*)d_in[3];
    const float* b2 = (const float*)d_in[4];
    const int* ei   = (const int*)d_in[5];
    const int* src  = ei;
    const int* dst  = ei + NE;
    const int* batch = (const int*)d_in[6];
    float* out = (float*)d_out;

    char* p = (char*)d_ws;
    int* deg     = (int*)p;            p += (size_t)NN * 4;        // 200000
    int* rowptr  = (int*)p;            p += (size_t)(NN + 4) * 4;  // 200016
    int* cursor  = (int*)p;            p += (size_t)NN * 4;        // 200000
    int* csr_src = (int*)p;            p += (size_t)NE * 4;        // 2400000
    float* dinv  = (float*)p;          p += (size_t)NN * 4;        // 200000
    float* bufA  = (float*)p;          p += (size_t)NN * 128 * 4;  // 25.6MB
    float* bufB  = (float*)p;          p += (size_t)NN * 128 * 4;  // 25.6MB

    // ---- CSR build + normalization ----
    k_zero_deg<<<(NN + 255) / 256, 256, 0, stream>>>(deg);
    k_hist<<<(NE + 255) / 256, 256, 0, stream>>>(dst, deg);
    k_dinv<<<(NN + 255) / 256, 256, 0, stream>>>(deg, dinv);
    k_scan<<<1, 1024, 0, stream>>>(deg, rowptr, cursor);
    k_scatter<<<(NE + 255) / 256, 256, 0, stream>>>(src, dst, cursor, csr_src);

    // ---- layer 1: C=128 -> 128 ----
    k_gemm<128, 128><<<NN / 8, 256, 0, stream>>>(x, W1, bufA);           // bufA = x@W1
    k_agg<128, true><<<NN / 8, 256, 0, stream>>>(rowptr, csr_src, dinv, bufA, b1, bufB);

    // ---- layer 2: C=128 -> 64 ----
    k_gemm<128, 64><<<NN / 16, 256, 0, stream>>>(bufB, W2, bufA);        // bufA = h1@W2
    k_agg<64, false><<<NN / 16, 256, 0, stream>>>(rowptr, csr_src, dinv, bufA, b2 /*unused*/, bufB);

    // ---- per-graph mean pool (+b2) ----
    k_pool<<<NG, 256, 0, stream>>>(bufB, batch, b2, out);
}

// Round 3
// 374.998 us; speedup vs baseline: 5.5934x; 1.2585x over previous
//
#include <hip/hip_runtime.h>

#define NN 50000
#define NE 600000
#define NG 64
#define SCAN_T 1024
#define SCAN_NB ((NN + SCAN_T - 1) / SCAN_T)  // 49

// ---------------- degree histogram (int) ----------------
__global__ void k_zero_deg(int* __restrict__ deg) {
    int i = blockIdx.x * blockDim.x + threadIdx.x;
    if (i < NN) deg[i] = 0;
}

__global__ void k_hist(const int* __restrict__ dst, int* __restrict__ deg) {
    int e = blockIdx.x * blockDim.x + threadIdx.x;
    if (e < NE) atomicAdd(&deg[dst[e]], 1);
}

// ---------------- 3-level parallel exclusive scan ----------------
__global__ __launch_bounds__(SCAN_T) void k_scan1(const int* __restrict__ deg,
                                                  int* __restrict__ blockSums) {
    __shared__ int s[SCAN_T];
    int i = blockIdx.x * SCAN_T + threadIdx.x;
    s[threadIdx.x] = (i < NN) ? deg[i] : 0;
    __syncthreads();
    for (int off = SCAN_T / 2; off > 0; off >>= 1) {
        if (threadIdx.x < off) s[threadIdx.x] += s[threadIdx.x + off];
        __syncthreads();
    }
    if (threadIdx.x == 0) blockSums[blockIdx.x] = s[0];
}

__global__ void k_scan2(const int* __restrict__ blockSums, int* __restrict__ blockOffs) {
    int t = threadIdx.x;  // one wave (64 lanes), SCAN_NB=49 <= 64
    int orig = (t < SCAN_NB) ? blockSums[t] : 0;
    int v = orig;
    for (int off = 1; off < 64; off <<= 1) {
        int u = __shfl_up(v, off);
        if (t >= off) v += u;
    }
    if (t < SCAN_NB) blockOffs[t] = v - orig;  // exclusive
}

__global__ __launch_bounds__(SCAN_T) void k_scan3(const int* __restrict__ deg,
                                                  const int* __restrict__ blockOffs,
                                                  int* __restrict__ rowptr,
                                                  int* __restrict__ cursor,
                                                  float* __restrict__ dinv) {
    __shared__ int s[SCAN_T];
    const int t = threadIdx.x;
    const int i = blockIdx.x * SCAN_T + t;
    const int v = (i < NN) ? deg[i] : 0;
    s[t] = v;
    __syncthreads();
    for (int off = 1; off < SCAN_T; off <<= 1) {
        int u = (t >= off) ? s[t - off] : 0;
        int cur = s[t];
        __syncthreads();
        s[t] = cur + u;
        __syncthreads();
    }
    if (i < NN) {
        int ex = blockOffs[blockIdx.x] + s[t] - v;  // exclusive prefix
        rowptr[i] = ex;
        cursor[i] = ex;
        dinv[i] = rsqrtf((float)(v + 1));
    }
    if (i == 0) rowptr[NN] = NE;  // every edge's dst is in-range
}

// ---------------- scatter edges into CSR buckets ----------------
__global__ void k_scatter(const int* __restrict__ src, const int* __restrict__ dst,
                          int* __restrict__ cursor, int* __restrict__ csr_src) {
    int e = blockIdx.x * blockDim.x + threadIdx.x;
    if (e >= NE) return;
    int d = dst[e];
    int p = atomicAdd(&cursor[d], 1);
    csr_src[p] = src[e];
}

// ---------------- dense GEMM: H[M,COUT] = X[M,CIN] @ W[CIN,COUT] ----------------
template <int CIN, int COUT>
__global__ __launch_bounds__(256) void k_gemm(const float* __restrict__ X,
                                              const float* __restrict__ W,
                                              float* __restrict__ H) {
    constexpr int TPR = COUT / 4;      // threads per row
    constexpr int RPB = 256 / TPR;     // rows per block
    constexpr int F4R = CIN / 4;
    __shared__ float xs[RPB][CIN + 4];
    const int tid = threadIdx.x;
    const long row0 = (long)blockIdx.x * RPB;

    for (int idx = tid; idx < RPB * F4R; idx += 256) {
        int r = idx / F4R, c4 = idx % F4R;
        long row = row0 + r;
        float4 v = make_float4(0.f, 0.f, 0.f, 0.f);
        if (row < NN) v = ((const float4*)X)[row * F4R + c4];
        xs[r][c4 * 4 + 0] = v.x; xs[r][c4 * 4 + 1] = v.y;
        xs[r][c4 * 4 + 2] = v.z; xs[r][c4 * 4 + 3] = v.w;
    }
    __syncthreads();

    const int r = tid / TPR;
    const int j = (tid % TPR) * 4;
    const long row = row0 + r;
    if (row >= NN) return;

    float4 acc = make_float4(0.f, 0.f, 0.f, 0.f);
#pragma unroll 8
    for (int k = 0; k < CIN; ++k) {
        float xv = xs[r][k];
        float4 w = *(const float4*)&W[k * COUT + j];
        acc.x += xv * w.x; acc.y += xv * w.y;
        acc.z += xv * w.z; acc.w += xv * w.w;
    }
    *(float4*)&H[row * COUT + j] = acc;
}

// ---------------- gather aggregation: OUT[d] = sum_in(H[s]*dinv[s])*dinv[d] + self ----------------
template <int C, bool BIAS_RELU>
__global__ __launch_bounds__(256) void k_agg(const int* __restrict__ rowptr,
                                             const int* __restrict__ csr_src,
                                             const float* __restrict__ dinv,
                                             const float* __restrict__ H,
                                             const float* __restrict__ bias,
                                             float* __restrict__ OUT) {
    constexpr int TPN = C / 4;        // threads per node (float4 channels)
    constexpr int NPB = 256 / TPN;    // nodes per block
    const int node = blockIdx.x * NPB + threadIdx.x / TPN;
    if (node >= NN) return;
    const int lane = threadIdx.x % TPN;
    const float dd = dinv[node];
    const float4* __restrict__ H4 = (const float4*)H;

    // self-loop term: H[node] * dinv[node]^2
    float4 v = H4[(long)node * TPN + lane];
    const float w = dd * dd;
    float4 acc = make_float4(v.x * w, v.y * w, v.z * w, v.w * w);

    const int beg = rowptr[node], end = rowptr[node + 1];
    for (int k = beg; k < end; ++k) {
        int s = csr_src[k];
        float nrm = dinv[s] * dd;
        float4 h = H4[(long)s * TPN + lane];
        acc.x += h.x * nrm; acc.y += h.y * nrm;
        acc.z += h.z * nrm; acc.w += h.w * nrm;
    }
    if (BIAS_RELU) {
        float4 bb = ((const float4*)bias)[lane];
        acc.x = fmaxf(acc.x + bb.x, 0.f);
        acc.y = fmaxf(acc.y + bb.y, 0.f);
        acc.z = fmaxf(acc.z + bb.z, 0.f);
        acc.w = fmaxf(acc.w + bb.w, 0.f);
    }
    ((float4*)OUT)[(long)node * TPN + lane] = acc;
}

// ---------------- per-graph mean pool (batch sorted, binary search) ----------------
__global__ __launch_bounds__(256) void k_pool(const float* __restrict__ H,
                                              const int* __restrict__ batch,
                                              const float* __restrict__ b2,
                                              float* __restrict__ out) {
    const int g = blockIdx.x;  // one block per graph
    int beg, end;
    {
        int lo = 0, hi = NN;
        while (lo < hi) { int mid = (lo + hi) >> 1; if (batch[mid] < g) lo = mid + 1; else hi = mid; }
        beg = lo;
        lo = beg; hi = NN;
        while (lo < hi) { int mid = (lo + hi) >> 1; if (batch[mid] < g + 1) lo = mid + 1; else hi = mid; }
        end = lo;
    }
    const int ch = threadIdx.x & 63;
    const int sub = threadIdx.x >> 6;  // 0..3
    float s = 0.f;
    for (int n = beg + sub; n < end; n += 4) s += H[(long)n * 64 + ch];
    __shared__ float red[4][64];
    red[sub][ch] = s;
    __syncthreads();
    if (sub == 0) {
        float tot = red[0][ch] + red[1][ch] + red[2][ch] + red[3][ch];
        int cnt = end - beg;
        out[g * 64 + ch] = (cnt > 0) ? (tot / (float)cnt + b2[ch]) : 0.f;
    }
}

extern "C" void kernel_launch(void* const* d_in, const int* in_sizes, int n_in,
                              void* d_out, int out_size, void* d_ws, size_t ws_size,
                              hipStream_t stream) {
    const float* x  = (const float*)d_in[0];
    const float* W1 = (const float*)d_in[1];
    const float* b1 = (const float*)d_in[2];
    const float* W2 = (const float*)d_in[3];
    const float* b2 = (const float*)d_in[4];
    const int* ei   = (const int*)d_in[5];
    const int* src  = ei;
    const int* dst  = ei + NE;
    const int* batch = (const int*)d_in[6];
    float* out = (float*)d_out;

    char* p = (char*)d_ws;
    int* deg       = (int*)p;          p += (size_t)NN * 4;
    int* rowptr    = (int*)p;          p += (size_t)(NN + 4) * 4;
    int* cursor    = (int*)p;          p += (size_t)NN * 4;
    int* csr_src   = (int*)p;          p += (size_t)NE * 4;
    int* blockSums = (int*)p;          p += (size_t)64 * 4;
    int* blockOffs = (int*)p;          p += (size_t)64 * 4;
    float* dinv    = (float*)p;        p += (size_t)NN * 4;
    float* bufA    = (float*)p;        p += (size_t)NN * 128 * 4;
    float* bufB    = (float*)p;        p += (size_t)NN * 128 * 4;

    // ---- CSR build + normalization ----
    k_zero_deg<<<(NN + 255) / 256, 256, 0, stream>>>(deg);
    k_hist<<<(NE + 255) / 256, 256, 0, stream>>>(dst, deg);
    k_scan1<<<SCAN_NB, SCAN_T, 0, stream>>>(deg, blockSums);
    k_scan2<<<1, 64, 0, stream>>>(blockSums, blockOffs);
    k_scan3<<<SCAN_NB, SCAN_T, 0, stream>>>(deg, blockOffs, rowptr, cursor, dinv);
    k_scatter<<<(NE + 255) / 256, 256, 0, stream>>>(src, dst, cursor, csr_src);

    // ---- layer 1: C=128 -> 128 ----
    k_gemm<128, 128><<<NN / 8, 256, 0, stream>>>(x, W1, bufA);           // bufA = x@W1
    k_agg<128, true><<<NN / 8, 256, 0, stream>>>(rowptr, csr_src, dinv, bufA, b1, bufB);

    // ---- layer 2: C=128 -> 64 ----
    k_gemm<128, 64><<<NN / 16, 256, 0, stream>>>(bufB, W2, bufA);        // bufA = h1@W2
    k_agg<64, false><<<NN / 16, 256, 0, stream>>>(rowptr, csr_src, dinv, bufA, b2 /*unused*/, bufB);

    // ---- per-graph mean pool (+b2) ----
    k_pool<<<NG, 256, 0, stream>>>(bufB, batch, b2, out);
}

// Round 4
// 287.060 us; speedup vs baseline: 7.3069x; 1.3063x over previous
//
#include <hip/hip_runtime.h>

#define NN 50000
#define NE 600000
#define NG 64
#define SCAN_T 1024
#define SCAN_NB ((NN + SCAN_T - 1) / SCAN_T)  // 49

// ---------------- degree histogram (int) ----------------
__global__ void k_zero_deg(int* __restrict__ deg) {
    int i = blockIdx.x * blockDim.x + threadIdx.x;
    if (i < NN) deg[i] = 0;
}

__global__ void k_hist(const int* __restrict__ dst, int* __restrict__ deg) {
    int e = blockIdx.x * blockDim.x + threadIdx.x;
    if (e < NE) atomicAdd(&deg[dst[e]], 1);
}

// ---------------- 3-level parallel exclusive scan ----------------
__global__ __launch_bounds__(SCAN_T) void k_scan1(const int* __restrict__ deg,
                                                  int* __restrict__ blockSums) {
    __shared__ int s[SCAN_T];
    int i = blockIdx.x * SCAN_T + threadIdx.x;
    s[threadIdx.x] = (i < NN) ? deg[i] : 0;
    __syncthreads();
    for (int off = SCAN_T / 2; off > 0; off >>= 1) {
        if (threadIdx.x < off) s[threadIdx.x] += s[threadIdx.x + off];
        __syncthreads();
    }
    if (threadIdx.x == 0) blockSums[blockIdx.x] = s[0];
}

__global__ void k_scan2(const int* __restrict__ blockSums, int* __restrict__ blockOffs) {
    int t = threadIdx.x;  // one wave (64 lanes), SCAN_NB=49 <= 64
    int orig = (t < SCAN_NB) ? blockSums[t] : 0;
    int v = orig;
    for (int off = 1; off < 64; off <<= 1) {
        int u = __shfl_up(v, off);
        if (t >= off) v += u;
    }
    if (t < SCAN_NB) blockOffs[t] = v - orig;  // exclusive
}

__global__ __launch_bounds__(SCAN_T) void k_scan3(const int* __restrict__ deg,
                                                  const int* __restrict__ blockOffs,
                                                  int* __restrict__ rowptr,
                                                  int* __restrict__ cursor,
                                                  float* __restrict__ dinv) {
    __shared__ int s[SCAN_T];
    const int t = threadIdx.x;
    const int i = blockIdx.x * SCAN_T + t;
    const int v = (i < NN) ? deg[i] : 0;
    s[t] = v;
    __syncthreads();
    for (int off = 1; off < SCAN_T; off <<= 1) {
        int u = (t >= off) ? s[t - off] : 0;
        int cur = s[t];
        __syncthreads();
        s[t] = cur + u;
        __syncthreads();
    }
    if (i < NN) {
        int ex = blockOffs[blockIdx.x] + s[t] - v;  // exclusive prefix
        rowptr[i] = ex;
        cursor[i] = ex;
        dinv[i] = rsqrtf((float)(v + 1));
    }
    if (i == 0) rowptr[NN] = NE;  // every edge's dst is in-range
}

// ---------------- scatter edges into CSR buckets ----------------
__global__ void k_scatter(const int* __restrict__ src, const int* __restrict__ dst,
                          int* __restrict__ cursor, int* __restrict__ csr_src) {
    int e = blockIdx.x * blockDim.x + threadIdx.x;
    if (e >= NE) return;
    int d = dst[e];
    int p = atomicAdd(&cursor[d], 1);
    csr_src[p] = src[e];
}

// ---------------- register-blocked GEMM: H[M,COUT] = X[M,CIN] @ W[CIN,COUT] ----------------
// Each thread: RPT rows x 4 cols. Block: 256 threads, BM = (256/(COUT/4))*RPT rows.
template <int CIN, int COUT, int RPT>
__global__ __launch_bounds__(256) void k_gemm(const float* __restrict__ X,
                                              const float* __restrict__ W,
                                              float* __restrict__ H) {
    constexpr int TPR = COUT / 4;        // threads across cols
    constexpr int NGRP = 256 / TPR;      // row groups
    constexpr int BM = NGRP * RPT;       // rows per block
    constexpr int LDW = CIN + 4;         // LDS row stride (pad, keeps 16B align)
    constexpr int F4R = CIN / 4;
    __shared__ float xs[BM][LDW];
    const int tid = threadIdx.x;
    const int row0 = blockIdx.x * BM;

    // stage X tile
    for (int idx = tid; idx < BM * F4R; idx += 256) {
        int r = idx / F4R, c4 = idx % F4R;
        int row = row0 + r;
        float4 v = make_float4(0.f, 0.f, 0.f, 0.f);
        if (row < NN) v = ((const float4*)X)[(long)row * F4R + c4];
        *(float4*)&xs[r][c4 * 4] = v;
    }
    __syncthreads();

    const int g = tid / TPR;             // row group
    const int j = (tid % TPR) * 4;       // col
    const int r0 = g * RPT;

    float4 acc[RPT];
#pragma unroll
    for (int r = 0; r < RPT; ++r) acc[r] = make_float4(0.f, 0.f, 0.f, 0.f);

    for (int k = 0; k < CIN; k += 4) {
        const float4 w0 = *(const float4*)&W[(k + 0) * COUT + j];
        const float4 w1 = *(const float4*)&W[(k + 1) * COUT + j];
        const float4 w2 = *(const float4*)&W[(k + 2) * COUT + j];
        const float4 w3 = *(const float4*)&W[(k + 3) * COUT + j];
#pragma unroll
        for (int r = 0; r < RPT; ++r) {
            const float4 xv = *(const float4*)&xs[r0 + r][k];
            acc[r].x += xv.x * w0.x + xv.y * w1.x + xv.z * w2.x + xv.w * w3.x;
            acc[r].y += xv.x * w0.y + xv.y * w1.y + xv.z * w2.y + xv.w * w3.y;
            acc[r].z += xv.x * w0.z + xv.y * w1.z + xv.z * w2.z + xv.w * w3.z;
            acc[r].w += xv.x * w0.w + xv.y * w1.w + xv.z * w2.w + xv.w * w3.w;
        }
    }

#pragma unroll
    for (int r = 0; r < RPT; ++r) {
        int row = row0 + r0 + r;
        if (row < NN) *(float4*)&H[(long)row * COUT + j] = acc[r];
    }
}

// ---------------- gather aggregation: OUT[d] = sum_in(H[s]*dinv[s])*dinv[d] + self ----------------
template <int C, bool BIAS_RELU>
__global__ __launch_bounds__(256) void k_agg(const int* __restrict__ rowptr,
                                             const int* __restrict__ csr_src,
                                             const float* __restrict__ dinv,
                                             const float* __restrict__ H,
                                             const float* __restrict__ bias,
                                             float* __restrict__ OUT) {
    constexpr int TPN = C / 4;        // threads per node (float4 channels)
    constexpr int NPB = 256 / TPN;    // nodes per block
    const int node = blockIdx.x * NPB + threadIdx.x / TPN;
    if (node >= NN) return;
    const int lane = threadIdx.x % TPN;
    const float dd = dinv[node];
    const float4* __restrict__ H4 = (const float4*)H;

    // self-loop term: H[node] * dinv[node]^2
    float4 v = H4[(long)node * TPN + lane];
    const float w = dd * dd;
    float4 acc = make_float4(v.x * w, v.y * w, v.z * w, v.w * w);

    const int beg = rowptr[node], end = rowptr[node + 1];
    for (int k = beg; k < end; ++k) {
        int s = csr_src[k];
        float nrm = dinv[s] * dd;
        float4 h = H4[(long)s * TPN + lane];
        acc.x += h.x * nrm; acc.y += h.y * nrm;
        acc.z += h.z * nrm; acc.w += h.w * nrm;
    }
    if (BIAS_RELU) {
        float4 bb = ((const float4*)bias)[lane];
        acc.x = fmaxf(acc.x + bb.x, 0.f);
        acc.y = fmaxf(acc.y + bb.y, 0.f);
        acc.z = fmaxf(acc.z + bb.z, 0.f);
        acc.w = fmaxf(acc.w + bb.w, 0.f);
    }
    ((float4*)OUT)[(long)node * TPN + lane] = acc;
}

// ---------------- per-graph mean pool (batch sorted, binary search) ----------------
__global__ __launch_bounds__(256) void k_pool(const float* __restrict__ H,
                                              const int* __restrict__ batch,
                                              const float* __restrict__ b2,
                                              float* __restrict__ out) {
    const int g = blockIdx.x;  // one block per graph
    int beg, end;
    {
        int lo = 0, hi = NN;
        while (lo < hi) { int mid = (lo + hi) >> 1; if (batch[mid] < g) lo = mid + 1; else hi = mid; }
        beg = lo;
        lo = beg; hi = NN;
        while (lo < hi) { int mid = (lo + hi) >> 1; if (batch[mid] < g + 1) lo = mid + 1; else hi = mid; }
        end = lo;
    }
    const int ch = threadIdx.x & 63;
    const int sub = threadIdx.x >> 6;  // 0..3
    float s = 0.f;
    for (int n = beg + sub; n < end; n += 4) s += H[(long)n * 64 + ch];
    __shared__ float red[4][64];
    red[sub][ch] = s;
    __syncthreads();
    if (sub == 0) {
        float tot = red[0][ch] + red[1][ch] + red[2][ch] + red[3][ch];
        int cnt = end - beg;
        out[g * 64 + ch] = (cnt > 0) ? (tot / (float)cnt + b2[ch]) : 0.f;
    }
}

extern "C" void kernel_launch(void* const* d_in, const int* in_sizes, int n_in,
                              void* d_out, int out_size, void* d_ws, size_t ws_size,
                              hipStream_t stream) {
    const float* x  = (const float*)d_in[0];
    const float* W1 = (const float*)d_in[1];
    const float* b1 = (const float*)d_in[2];
    const float* W2 = (const float*)d_in[3];
    const float* b2 = (const float*)d_in[4];
    const int* ei   = (const int*)d_in[5];
    const int* src  = ei;
    const int* dst  = ei + NE;
    const int* batch = (const int*)d_in[6];
    float* out = (float*)d_out;

    char* p = (char*)d_ws;
    int* deg       = (int*)p;          p += (size_t)NN * 4;
    int* rowptr    = (int*)p;          p += (size_t)(NN + 4) * 4;
    int* cursor    = (int*)p;          p += (size_t)NN * 4;
    int* csr_src   = (int*)p;          p += (size_t)NE * 4;
    int* blockSums = (int*)p;          p += (size_t)64 * 4;
    int* blockOffs = (int*)p;          p += (size_t)64 * 4;
    float* dinv    = (float*)p;        p += (size_t)NN * 4;
    float* bufA    = (float*)p;        p += (size_t)NN * 128 * 4;
    float* bufB    = (float*)p;        p += (size_t)NN * 128 * 4;

    // ---- CSR build + normalization ----
    k_zero_deg<<<(NN + 255) / 256, 256, 0, stream>>>(deg);
    k_hist<<<(NE + 255) / 256, 256, 0, stream>>>(dst, deg);
    k_scan1<<<SCAN_NB, SCAN_T, 0, stream>>>(deg, blockSums);
    k_scan2<<<1, 64, 0, stream>>>(blockSums, blockOffs);
    k_scan3<<<SCAN_NB, SCAN_T, 0, stream>>>(deg, blockOffs, rowptr, cursor, dinv);
    k_scatter<<<(NE + 255) / 256, 256, 0, stream>>>(src, dst, cursor, csr_src);

    // ---- layer 1: C=128 -> 128 ----
    // BM = (256/32)*8 = 64 rows/block
    k_gemm<128, 128, 8><<<(NN + 63) / 64, 256, 0, stream>>>(x, W1, bufA);
    k_agg<128, true><<<NN / 8, 256, 0, stream>>>(rowptr, csr_src, dinv, bufA, b1, bufB);

    // ---- layer 2: C=128 -> 64 ----
    // BM = (256/16)*4 = 64 rows/block
    k_gemm<128, 64, 4><<<(NN + 63) / 64, 256, 0, stream>>>(bufB, W2, bufA);
    k_agg<64, false><<<NN / 16, 256, 0, stream>>>(rowptr, csr_src, dinv, bufA, b2 /*unused*/, bufB);

    // ---- per-graph mean pool (+b2) ----
    k_pool<<<NG, 256, 0, stream>>>(bufB, batch, b2, out);
}

// Round 5
// 237.297 us; speedup vs baseline: 8.8392x; 1.2097x over previous
//
#include <hip/hip_runtime.h>

#define NN 50000
#define NE 600000
#define NG 64
#define SCAN_T 1024
#define SCAN_NB ((NN + SCAN_T - 1) / SCAN_T)  // 49
#define PSPLIT 16

// ---------------- degree histogram (int) ----------------
__global__ void k_zero_deg(int* __restrict__ deg) {
    int i = blockIdx.x * blockDim.x + threadIdx.x;
    if (i < NN) deg[i] = 0;
}

__global__ void k_hist(const int* __restrict__ dst, int* __restrict__ deg) {
    int e = blockIdx.x * blockDim.x + threadIdx.x;
    if (e < NE) atomicAdd(&deg[dst[e]], 1);
}

// ---------------- 3-level parallel exclusive scan ----------------
__global__ __launch_bounds__(SCAN_T) void k_scan1(const int* __restrict__ deg,
                                                  int* __restrict__ blockSums) {
    __shared__ int s[SCAN_T];
    int i = blockIdx.x * SCAN_T + threadIdx.x;
    s[threadIdx.x] = (i < NN) ? deg[i] : 0;
    __syncthreads();
    for (int off = SCAN_T / 2; off > 0; off >>= 1) {
        if (threadIdx.x < off) s[threadIdx.x] += s[threadIdx.x + off];
        __syncthreads();
    }
    if (threadIdx.x == 0) blockSums[blockIdx.x] = s[0];
}

__global__ void k_scan2(const int* __restrict__ blockSums, int* __restrict__ blockOffs) {
    int t = threadIdx.x;  // one wave (64 lanes), SCAN_NB=49 <= 64
    int orig = (t < SCAN_NB) ? blockSums[t] : 0;
    int v = orig;
    for (int off = 1; off < 64; off <<= 1) {
        int u = __shfl_up(v, off);
        if (t >= off) v += u;
    }
    if (t < SCAN_NB) blockOffs[t] = v - orig;  // exclusive
}

__global__ __launch_bounds__(SCAN_T) void k_scan3(const int* __restrict__ deg,
                                                  const int* __restrict__ blockOffs,
                                                  int* __restrict__ rowptr,
                                                  int* __restrict__ cursor,
                                                  float* __restrict__ dinv) {
    __shared__ int s[SCAN_T];
    const int t = threadIdx.x;
    const int i = blockIdx.x * SCAN_T + t;
    const int v = (i < NN) ? deg[i] : 0;
    s[t] = v;
    __syncthreads();
    for (int off = 1; off < SCAN_T; off <<= 1) {
        int u = (t >= off) ? s[t - off] : 0;
        int cur = s[t];
        __syncthreads();
        s[t] = cur + u;
        __syncthreads();
    }
    if (i < NN) {
        int ex = blockOffs[blockIdx.x] + s[t] - v;  // exclusive prefix
        rowptr[i] = ex;
        cursor[i] = ex;
        dinv[i] = rsqrtf((float)(v + 1));
    }
    if (i == 0) rowptr[NN] = NE;  // every edge's dst is in-range
}

// ---------------- scatter edges into CSR buckets ----------------
__global__ void k_scatter(const int* __restrict__ src, const int* __restrict__ dst,
                          int* __restrict__ cursor, int* __restrict__ csr_src) {
    int e = blockIdx.x * blockDim.x + threadIdx.x;
    if (e >= NE) return;
    int d = dst[e];
    int p = atomicAdd(&cursor[d], 1);
    csr_src[p] = src[e];
}

// ---------------- register-blocked GEMM: H[M,COUT] = X[M,CIN] @ W[CIN,COUT] ----------------
template <int CIN, int COUT, int RPT>
__global__ __launch_bounds__(256) void k_gemm(const float* __restrict__ X,
                                              const float* __restrict__ W,
                                              float* __restrict__ H) {
    constexpr int TPR = COUT / 4;        // threads across cols
    constexpr int NGRP = 256 / TPR;      // row groups
    constexpr int BM = NGRP * RPT;       // rows per block
    constexpr int LDW = CIN + 4;         // LDS row stride (pad, keeps 16B align)
    constexpr int F4R = CIN / 4;
    __shared__ float xs[BM][LDW];
    const int tid = threadIdx.x;
    const int row0 = blockIdx.x * BM;

    for (int idx = tid; idx < BM * F4R; idx += 256) {
        int r = idx / F4R, c4 = idx % F4R;
        int row = row0 + r;
        float4 v = make_float4(0.f, 0.f, 0.f, 0.f);
        if (row < NN) v = ((const float4*)X)[(long)row * F4R + c4];
        *(float4*)&xs[r][c4 * 4] = v;
    }
    __syncthreads();

    const int g = tid / TPR;             // row group
    const int j = (tid % TPR) * 4;       // col
    const int r0 = g * RPT;

    float4 acc[RPT];
#pragma unroll
    for (int r = 0; r < RPT; ++r) acc[r] = make_float4(0.f, 0.f, 0.f, 0.f);

    for (int k = 0; k < CIN; k += 4) {
        const float4 w0 = *(const float4*)&W[(k + 0) * COUT + j];
        const float4 w1 = *(const float4*)&W[(k + 1) * COUT + j];
        const float4 w2 = *(const float4*)&W[(k + 2) * COUT + j];
        const float4 w3 = *(const float4*)&W[(k + 3) * COUT + j];
#pragma unroll
        for (int r = 0; r < RPT; ++r) {
            const float4 xv = *(const float4*)&xs[r0 + r][k];
            acc[r].x += xv.x * w0.x + xv.y * w1.x + xv.z * w2.x + xv.w * w3.x;
            acc[r].y += xv.x * w0.y + xv.y * w1.y + xv.z * w2.y + xv.w * w3.y;
            acc[r].z += xv.x * w0.z + xv.y * w1.z + xv.z * w2.z + xv.w * w3.z;
            acc[r].w += xv.x * w0.w + xv.y * w1.w + xv.z * w2.w + xv.w * w3.w;
        }
    }

#pragma unroll
    for (int r = 0; r < RPT; ++r) {
        int row = row0 + r0 + r;
        if (row < NN) *(float4*)&H[(long)row * COUT + j] = acc[r];
    }
}

// ---------------- gather aggregation: OUT[d] = sum_in(H[s]*dinv[s])*dinv[d] + self ----------------
template <int C, bool BIAS_RELU>
__global__ __launch_bounds__(256) void k_agg(const int* __restrict__ rowptr,
                                             const int* __restrict__ csr_src,
                                             const float* __restrict__ dinv,
                                             const float* __restrict__ H,
                                             const float* __restrict__ bias,
                                             float* __restrict__ OUT) {
    constexpr int TPN = C / 4;        // threads per node (float4 channels)
    constexpr int NPB = 256 / TPN;    // nodes per block
    const int node = blockIdx.x * NPB + threadIdx.x / TPN;
    if (node >= NN) return;
    const int lane = threadIdx.x % TPN;
    const float dd = dinv[node];
    const float4* __restrict__ H4 = (const float4*)H;

    float4 v = H4[(long)node * TPN + lane];
    const float w = dd * dd;
    float4 acc = make_float4(v.x * w, v.y * w, v.z * w, v.w * w);

    const int beg = rowptr[node], end = rowptr[node + 1];
    for (int k = beg; k < end; ++k) {
        int s = csr_src[k];
        float nrm = dinv[s] * dd;
        float4 h = H4[(long)s * TPN + lane];
        acc.x += h.x * nrm; acc.y += h.y * nrm;
        acc.z += h.z * nrm; acc.w += h.w * nrm;
    }
    if (BIAS_RELU) {
        float4 bb = ((const float4*)bias)[lane];
        acc.x = fmaxf(acc.x + bb.x, 0.f);
        acc.y = fmaxf(acc.y + bb.y, 0.f);
        acc.z = fmaxf(acc.z + bb.z, 0.f);
        acc.w = fmaxf(acc.w + bb.w, 0.f);
    }
    ((float4*)OUT)[(long)node * TPN + lane] = acc;
}

// ---------------- two-stage per-graph mean pool (batch sorted) ----------------
// stage 1: NG*PSPLIT blocks; block (g,s) sums nodes n in [beg,end) with
//          (n-beg) % (PSPLIT*16) in [s*16, s*16+16) -> partial[g*PSPLIT+s][64]
__global__ __launch_bounds__(256) void k_pool1(const float* __restrict__ H,
                                               const int* __restrict__ batch,
                                               float* __restrict__ partial) {
    const int g = blockIdx.x / PSPLIT;
    const int s = blockIdx.x % PSPLIT;
    int beg, end;
    {
        int lo = 0, hi = NN;
        while (lo < hi) { int mid = (lo + hi) >> 1; if (batch[mid] < g) lo = mid + 1; else hi = mid; }
        beg = lo;
        lo = beg; hi = NN;
        while (lo < hi) { int mid = (lo + hi) >> 1; if (batch[mid] < g + 1) lo = mid + 1; else hi = mid; }
        end = lo;
    }
    const int c4 = threadIdx.x & 15;   // float4 channel group (64 ch = 16 float4)
    const int rg = threadIdx.x >> 4;   // 0..15 node subgroup
    const float4* __restrict__ H4 = (const float4*)H;

    float4 acc = make_float4(0.f, 0.f, 0.f, 0.f);
    for (int n = beg + s * 16 + rg; n < end; n += PSPLIT * 16) {
        float4 h = H4[(long)n * 16 + c4];
        acc.x += h.x; acc.y += h.y; acc.z += h.z; acc.w += h.w;
    }
    __shared__ float4 red[16][17];
    red[rg][c4] = acc;
    __syncthreads();
    if (rg == 0) {
        float4 t = red[0][c4];
#pragma unroll
        for (int i = 1; i < 16; ++i) {
            float4 u = red[i][c4];
            t.x += u.x; t.y += u.y; t.z += u.z; t.w += u.w;
        }
        ((float4*)partial)[(long)blockIdx.x * 16 + c4] = t;
    }
}

// stage 2: NG blocks x 64 threads: reduce PSPLIT partials, divide by count, +b2
__global__ __launch_bounds__(64) void k_pool2(const float* __restrict__ partial,
                                              const int* __restrict__ batch,
                                              const float* __restrict__ b2,
                                              float* __restrict__ out) {
    const int g = blockIdx.x;
    const int ch = threadIdx.x;
    int beg, end;
    {
        int lo = 0, hi = NN;
        while (lo < hi) { int mid = (lo + hi) >> 1; if (batch[mid] < g) lo = mid + 1; else hi = mid; }
        beg = lo;
        lo = beg; hi = NN;
        while (lo < hi) { int mid = (lo + hi) >> 1; if (batch[mid] < g + 1) lo = mid + 1; else hi = mid; }
        end = lo;
    }
    float s = 0.f;
    for (int i = 0; i < PSPLIT; ++i) s += partial[(long)(g * PSPLIT + i) * 64 + ch];
    int cnt = end - beg;
    out[g * 64 + ch] = (cnt > 0) ? (s / (float)cnt + b2[ch]) : 0.f;
}

extern "C" void kernel_launch(void* const* d_in, const int* in_sizes, int n_in,
                              void* d_out, int out_size, void* d_ws, size_t ws_size,
                              hipStream_t stream) {
    const float* x  = (const float*)d_in[0];
    const float* W1 = (const float*)d_in[1];
    const float* b1 = (const float*)d_in[2];
    const float* W2 = (const float*)d_in[3];
    const float* b2 = (const float*)d_in[4];
    const int* ei   = (const int*)d_in[5];
    const int* src  = ei;
    const int* dst  = ei + NE;
    const int* batch = (const int*)d_in[6];
    float* out = (float*)d_out;

    char* p = (char*)d_ws;
    int* deg       = (int*)p;          p += (size_t)NN * 4;
    int* rowptr    = (int*)p;          p += (size_t)(NN + 4) * 4;
    int* cursor    = (int*)p;          p += (size_t)NN * 4;
    int* csr_src   = (int*)p;          p += (size_t)NE * 4;
    int* blockSums = (int*)p;          p += (size_t)64 * 4;
    int* blockOffs = (int*)p;          p += (size_t)64 * 4;
    float* dinv    = (float*)p;        p += (size_t)NN * 4;
    float* partial = (float*)p;        p += (size_t)NG * PSPLIT * 64 * 4;
    float* bufA    = (float*)p;        p += (size_t)NN * 128 * 4;
    float* bufB    = (float*)p;        p += (size_t)NN * 128 * 4;

    // ---- CSR build + normalization ----
    k_zero_deg<<<(NN + 255) / 256, 256, 0, stream>>>(deg);
    k_hist<<<(NE + 255) / 256, 256, 0, stream>>>(dst, deg);
    k_scan1<<<SCAN_NB, SCAN_T, 0, stream>>>(deg, blockSums);
    k_scan2<<<1, 64, 0, stream>>>(blockSums, blockOffs);
    k_scan3<<<SCAN_NB, SCAN_T, 0, stream>>>(deg, blockOffs, rowptr, cursor, dinv);
    k_scatter<<<(NE + 255) / 256, 256, 0, stream>>>(src, dst, cursor, csr_src);

    // ---- layer 1: C=128 -> 128 ----
    k_gemm<128, 128, 8><<<(NN + 63) / 64, 256, 0, stream>>>(x, W1, bufA);
    k_agg<128, true><<<NN / 8, 256, 0, stream>>>(rowptr, csr_src, dinv, bufA, b1, bufB);

    // ---- layer 2: C=128 -> 64 ----
    k_gemm<128, 64, 4><<<(NN + 63) / 64, 256, 0, stream>>>(bufB, W2, bufA);
    k_agg<64, false><<<NN / 16, 256, 0, stream>>>(rowptr, csr_src, dinv, bufA, b2 /*unused*/, bufB);

    // ---- two-stage per-graph mean pool (+b2) ----
    k_pool1<<<NG * PSPLIT, 256, 0, stream>>>(bufB, batch, partial);
    k_pool2<<<NG, 64, 0, stream>>>(partial, batch, b2, out);
}

// Round 6
// 227.477 us; speedup vs baseline: 9.2208x; 1.0432x over previous
//
#include <hip/hip_runtime.h>

#define NN 50000
#define NE 600000
#define NG 64
#define SCAN_T 1024
#define SCAN_NB ((NN + SCAN_T - 1) / SCAN_T)  // 49
#define PSPLIT 16

// ---------------- degree histogram (int) ----------------
__global__ void k_zero_deg(int* __restrict__ deg) {
    int i = blockIdx.x * blockDim.x + threadIdx.x;
    if (i < NN) deg[i] = 0;
}

__global__ void k_hist(const int* __restrict__ dst, int* __restrict__ deg) {
    int e = blockIdx.x * blockDim.x + threadIdx.x;
    if (e < NE) atomicAdd(&deg[dst[e]], 1);
}

// ---------------- 3-level parallel exclusive scan ----------------
__global__ __launch_bounds__(SCAN_T) void k_scan1(const int* __restrict__ deg,
                                                  int* __restrict__ blockSums) {
    __shared__ int s[SCAN_T];
    int i = blockIdx.x * SCAN_T + threadIdx.x;
    s[threadIdx.x] = (i < NN) ? deg[i] : 0;
    __syncthreads();
    for (int off = SCAN_T / 2; off > 0; off >>= 1) {
        if (threadIdx.x < off) s[threadIdx.x] += s[threadIdx.x + off];
        __syncthreads();
    }
    if (threadIdx.x == 0) blockSums[blockIdx.x] = s[0];
}

__global__ void k_scan2(const int* __restrict__ blockSums, int* __restrict__ blockOffs) {
    int t = threadIdx.x;  // one wave (64 lanes), SCAN_NB=49 <= 64
    int orig = (t < SCAN_NB) ? blockSums[t] : 0;
    int v = orig;
    for (int off = 1; off < 64; off <<= 1) {
        int u = __shfl_up(v, off);
        if (t >= off) v += u;
    }
    if (t < SCAN_NB) blockOffs[t] = v - orig;  // exclusive
}

__global__ __launch_bounds__(SCAN_T) void k_scan3(const int* __restrict__ deg,
                                                  const int* __restrict__ blockOffs,
                                                  int* __restrict__ rowptr,
                                                  int* __restrict__ cursor,
                                                  float* __restrict__ dinv) {
    __shared__ int s[SCAN_T];
    const int t = threadIdx.x;
    const int i = blockIdx.x * SCAN_T + t;
    const int v = (i < NN) ? deg[i] : 0;
    s[t] = v;
    __syncthreads();
    for (int off = 1; off < SCAN_T; off <<= 1) {
        int u = (t >= off) ? s[t - off] : 0;
        int cur = s[t];
        __syncthreads();
        s[t] = cur + u;
        __syncthreads();
    }
    if (i < NN) {
        int ex = blockOffs[blockIdx.x] + s[t] - v;  // exclusive prefix
        rowptr[i] = ex;
        cursor[i] = ex;
        dinv[i] = rsqrtf((float)(v + 1));
    }
    if (i == 0) rowptr[NN] = NE;  // every edge's dst is in-range
}

// ---------------- scatter edges into CSR buckets ----------------
__global__ void k_scatter(const int* __restrict__ src, const int* __restrict__ dst,
                          int* __restrict__ cursor, int* __restrict__ csr_src) {
    int e = blockIdx.x * blockDim.x + threadIdx.x;
    if (e >= NE) return;
    int d = dst[e];
    int p = atomicAdd(&cursor[d], 1);
    csr_src[p] = src[e];
}

// ---------------- register-blocked GEMM, epilogue scales by dinv[row] ----------------
// Hs[row] = (X @ W)[row] * dinv[row]
template <int CIN, int COUT, int RPT>
__global__ __launch_bounds__(256) void k_gemm(const float* __restrict__ X,
                                              const float* __restrict__ W,
                                              const float* __restrict__ dinv,
                                              float* __restrict__ H) {
    constexpr int TPR = COUT / 4;        // threads across cols
    constexpr int NGRP = 256 / TPR;      // row groups
    constexpr int BM = NGRP * RPT;       // rows per block
    constexpr int LDW = CIN + 4;         // LDS row stride (pad, keeps 16B align)
    constexpr int F4R = CIN / 4;
    __shared__ float xs[BM][LDW];
    const int tid = threadIdx.x;
    const int row0 = blockIdx.x * BM;

    for (int idx = tid; idx < BM * F4R; idx += 256) {
        int r = idx / F4R, c4 = idx % F4R;
        int row = row0 + r;
        float4 v = make_float4(0.f, 0.f, 0.f, 0.f);
        if (row < NN) v = ((const float4*)X)[(long)row * F4R + c4];
        *(float4*)&xs[r][c4 * 4] = v;
    }
    __syncthreads();

    const int g = tid / TPR;             // row group
    const int j = (tid % TPR) * 4;       // col
    const int r0 = g * RPT;

    float4 acc[RPT];
#pragma unroll
    for (int r = 0; r < RPT; ++r) acc[r] = make_float4(0.f, 0.f, 0.f, 0.f);

    for (int k = 0; k < CIN; k += 4) {
        const float4 w0 = *(const float4*)&W[(k + 0) * COUT + j];
        const float4 w1 = *(const float4*)&W[(k + 1) * COUT + j];
        const float4 w2 = *(const float4*)&W[(k + 2) * COUT + j];
        const float4 w3 = *(const float4*)&W[(k + 3) * COUT + j];
#pragma unroll
        for (int r = 0; r < RPT; ++r) {
            const float4 xv = *(const float4*)&xs[r0 + r][k];
            acc[r].x += xv.x * w0.x + xv.y * w1.x + xv.z * w2.x + xv.w * w3.x;
            acc[r].y += xv.x * w0.y + xv.y * w1.y + xv.z * w2.y + xv.w * w3.y;
            acc[r].z += xv.x * w0.z + xv.y * w1.z + xv.z * w2.z + xv.w * w3.z;
            acc[r].w += xv.x * w0.w + xv.y * w1.w + xv.z * w2.w + xv.w * w3.w;
        }
    }

#pragma unroll
    for (int r = 0; r < RPT; ++r) {
        int row = row0 + r0 + r;
        if (row < NN) {
            float sc = dinv[row];
            acc[r].x *= sc; acc[r].y *= sc; acc[r].z *= sc; acc[r].w *= sc;
            *(float4*)&H[(long)row * COUT + j] = acc[r];
        }
    }
}

// ---------------- gather aggregation on pre-scaled Hs ----------------
// OUT[d] = dd * (Hs[d] + sum_in Hs[s])  [+bias, relu]
template <int C, bool BIAS_RELU>
__global__ __launch_bounds__(256) void k_agg(const int* __restrict__ rowptr,
                                             const int* __restrict__ csr_src,
                                             const float* __restrict__ dinv,
                                             const float* __restrict__ Hs,
                                             const float* __restrict__ bias,
                                             float* __restrict__ OUT) {
    constexpr int TPN = C / 4;        // threads per node (float4 channels)
    constexpr int NPB = 256 / TPN;    // nodes per block
    const int node = blockIdx.x * NPB + threadIdx.x / TPN;
    if (node >= NN) return;
    const int lane = threadIdx.x % TPN;
    const float dd = dinv[node];
    const float4* __restrict__ H4 = (const float4*)Hs;

    float4 acc = H4[(long)node * TPN + lane];  // self term (pre-scaled)

    const int beg = rowptr[node], end = rowptr[node + 1];
    int k = beg;
    const int n4 = beg + ((end - beg) & ~3);
    for (; k < n4; k += 4) {
        int s0 = csr_src[k + 0];
        int s1 = csr_src[k + 1];
        int s2 = csr_src[k + 2];
        int s3 = csr_src[k + 3];
        float4 h0 = H4[(long)s0 * TPN + lane];
        float4 h1 = H4[(long)s1 * TPN + lane];
        float4 h2 = H4[(long)s2 * TPN + lane];
        float4 h3 = H4[(long)s3 * TPN + lane];
        acc.x += (h0.x + h1.x) + (h2.x + h3.x);
        acc.y += (h0.y + h1.y) + (h2.y + h3.y);
        acc.z += (h0.z + h1.z) + (h2.z + h3.z);
        acc.w += (h0.w + h1.w) + (h2.w + h3.w);
    }
    for (; k < end; ++k) {
        int s = csr_src[k];
        float4 h = H4[(long)s * TPN + lane];
        acc.x += h.x; acc.y += h.y; acc.z += h.z; acc.w += h.w;
    }

    acc.x *= dd; acc.y *= dd; acc.z *= dd; acc.w *= dd;
    if (BIAS_RELU) {
        float4 bb = ((const float4*)bias)[lane];
        acc.x = fmaxf(acc.x + bb.x, 0.f);
        acc.y = fmaxf(acc.y + bb.y, 0.f);
        acc.z = fmaxf(acc.z + bb.z, 0.f);
        acc.w = fmaxf(acc.w + bb.w, 0.f);
    }
    ((float4*)OUT)[(long)node * TPN + lane] = acc;
}

// ---------------- two-stage per-graph mean pool (batch sorted) ----------------
__global__ __launch_bounds__(256) void k_pool1(const float* __restrict__ H,
                                               const int* __restrict__ batch,
                                               float* __restrict__ partial) {
    const int g = blockIdx.x / PSPLIT;
    const int s = blockIdx.x % PSPLIT;
    int beg, end;
    {
        int lo = 0, hi = NN;
        while (lo < hi) { int mid = (lo + hi) >> 1; if (batch[mid] < g) lo = mid + 1; else hi = mid; }
        beg = lo;
        lo = beg; hi = NN;
        while (lo < hi) { int mid = (lo + hi) >> 1; if (batch[mid] < g + 1) lo = mid + 1; else hi = mid; }
        end = lo;
    }
    const int c4 = threadIdx.x & 15;   // float4 channel group (64 ch = 16 float4)
    const int rg = threadIdx.x >> 4;   // 0..15 node subgroup
    const float4* __restrict__ H4 = (const float4*)H;

    float4 acc = make_float4(0.f, 0.f, 0.f, 0.f);
    for (int n = beg + s * 16 + rg; n < end; n += PSPLIT * 16) {
        float4 h = H4[(long)n * 16 + c4];
        acc.x += h.x; acc.y += h.y; acc.z += h.z; acc.w += h.w;
    }
    __shared__ float4 red[16][17];
    red[rg][c4] = acc;
    __syncthreads();
    if (rg == 0) {
        float4 t = red[0][c4];
#pragma unroll
        for (int i = 1; i < 16; ++i) {
            float4 u = red[i][c4];
            t.x += u.x; t.y += u.y; t.z += u.z; t.w += u.w;
        }
        ((float4*)partial)[(long)blockIdx.x * 16 + c4] = t;
    }
}

__global__ __launch_bounds__(64) void k_pool2(const float* __restrict__ partial,
                                              const int* __restrict__ batch,
                                              const float* __restrict__ b2,
                                              float* __restrict__ out) {
    const int g = blockIdx.x;
    const int ch = threadIdx.x;
    int beg, end;
    {
        int lo = 0, hi = NN;
        while (lo < hi) { int mid = (lo + hi) >> 1; if (batch[mid] < g) lo = mid + 1; else hi = mid; }
        beg = lo;
        lo = beg; hi = NN;
        while (lo < hi) { int mid = (lo + hi) >> 1; if (batch[mid] < g + 1) lo = mid + 1; else hi = mid; }
        end = lo;
    }
    float s = 0.f;
    for (int i = 0; i < PSPLIT; ++i) s += partial[(long)(g * PSPLIT + i) * 64 + ch];
    int cnt = end - beg;
    out[g * 64 + ch] = (cnt > 0) ? (s / (float)cnt + b2[ch]) : 0.f;
}

extern "C" void kernel_launch(void* const* d_in, const int* in_sizes, int n_in,
                              void* d_out, int out_size, void* d_ws, size_t ws_size,
                              hipStream_t stream) {
    const float* x  = (const float*)d_in[0];
    const float* W1 = (const float*)d_in[1];
    const float* b1 = (const float*)d_in[2];
    const float* W2 = (const float*)d_in[3];
    const float* b2 = (const float*)d_in[4];
    const int* ei   = (const int*)d_in[5];
    const int* src  = ei;
    const int* dst  = ei + NE;
    const int* batch = (const int*)d_in[6];
    float* out = (float*)d_out;

    char* p = (char*)d_ws;
    int* deg       = (int*)p;          p += (size_t)NN * 4;
    int* rowptr    = (int*)p;          p += (size_t)(NN + 4) * 4;
    int* cursor    = (int*)p;          p += (size_t)NN * 4;
    int* csr_src   = (int*)p;          p += (size_t)NE * 4;
    int* blockSums = (int*)p;          p += (size_t)64 * 4;
    int* blockOffs = (int*)p;          p += (size_t)64 * 4;
    float* dinv    = (float*)p;        p += (size_t)NN * 4;
    float* partial = (float*)p;        p += (size_t)NG * PSPLIT * 64 * 4;
    float* bufA    = (float*)p;        p += (size_t)NN * 128 * 4;
    float* bufB    = (float*)p;        p += (size_t)NN * 128 * 4;

    // ---- CSR build + normalization ----
    k_zero_deg<<<(NN + 255) / 256, 256, 0, stream>>>(deg);
    k_hist<<<(NE + 255) / 256, 256, 0, stream>>>(dst, deg);
    k_scan1<<<SCAN_NB, SCAN_T, 0, stream>>>(deg, blockSums);
    k_scan2<<<1, 64, 0, stream>>>(blockSums, blockOffs);
    k_scan3<<<SCAN_NB, SCAN_T, 0, stream>>>(deg, blockOffs, rowptr, cursor, dinv);
    k_scatter<<<(NE + 255) / 256, 256, 0, stream>>>(src, dst, cursor, csr_src);

    // ---- layer 1: C=128 -> 128 ----
    k_gemm<128, 128, 8><<<(NN + 63) / 64, 256, 0, stream>>>(x, W1, dinv, bufA);   // bufA = (x@W1)*dinv
    k_agg<128, true><<<NN / 8, 256, 0, stream>>>(rowptr, csr_src, dinv, bufA, b1, bufB);

    // ---- layer 2: C=128 -> 64 ----
    k_gemm<128, 64, 4><<<(NN + 63) / 64, 256, 0, stream>>>(bufB, W2, dinv, bufA); // bufA = (h1@W2)*dinv
    k_agg<64, false><<<NN / 16, 256, 0, stream>>>(rowptr, csr_src, dinv, bufA, b2 /*unused*/, bufB);

    // ---- two-stage per-graph mean pool (+b2) ----
    k_pool1<<<NG * PSPLIT, 256, 0, stream>>>(bufB, batch, partial);
    k_pool2<<<NG, 64, 0, stream>>>(partial, batch, b2, out);
}

// Round 7
// 194.263 us; speedup vs baseline: 10.7974x; 1.1710x over previous
//
#include <hip/hip_runtime.h>

#define NN 50000
#define NE 600000
#define NG 64
#define SCAN_T 1024
#define SCAN_NB ((NN + SCAN_T - 1) / SCAN_T)  // 49
#define PSPLIT 16

typedef unsigned int uint_t;
typedef unsigned short ushort_t;

__device__ __forceinline__ ushort_t f2bf(float x) {
    uint_t u = __builtin_bit_cast(uint_t, x);
    u = (u + 0x7FFFu + ((u >> 16) & 1u)) >> 16;  // round-to-nearest-even
    return (ushort_t)u;
}
__device__ __forceinline__ float bf_lo(uint_t p) {
    uint_t v = p << 16; return __builtin_bit_cast(float, v);
}
__device__ __forceinline__ float bf_hi(uint_t p) {
    uint_t v = p & 0xFFFF0000u; return __builtin_bit_cast(float, v);
}

// ---------------- degree histogram (int) ----------------
__global__ void k_zero_deg(int* __restrict__ deg) {
    int i = blockIdx.x * blockDim.x + threadIdx.x;
    if (i < NN) deg[i] = 0;
}

__global__ void k_hist(const int* __restrict__ dst, int* __restrict__ deg) {
    int e = blockIdx.x * blockDim.x + threadIdx.x;
    if (e < NE) atomicAdd(&deg[dst[e]], 1);
}

// ---------------- 3-level parallel exclusive scan ----------------
__global__ __launch_bounds__(SCAN_T) void k_scan1(const int* __restrict__ deg,
                                                  int* __restrict__ blockSums) {
    __shared__ int s[SCAN_T];
    int i = blockIdx.x * SCAN_T + threadIdx.x;
    s[threadIdx.x] = (i < NN) ? deg[i] : 0;
    __syncthreads();
    for (int off = SCAN_T / 2; off > 0; off >>= 1) {
        if (threadIdx.x < off) s[threadIdx.x] += s[threadIdx.x + off];
        __syncthreads();
    }
    if (threadIdx.x == 0) blockSums[blockIdx.x] = s[0];
}

__global__ void k_scan2(const int* __restrict__ blockSums, int* __restrict__ blockOffs) {
    int t = threadIdx.x;  // one wave (64 lanes), SCAN_NB=49 <= 64
    int orig = (t < SCAN_NB) ? blockSums[t] : 0;
    int v = orig;
    for (int off = 1; off < 64; off <<= 1) {
        int u = __shfl_up(v, off);
        if (t >= off) v += u;
    }
    if (t < SCAN_NB) blockOffs[t] = v - orig;  // exclusive
}

__global__ __launch_bounds__(SCAN_T) void k_scan3(const int* __restrict__ deg,
                                                  const int* __restrict__ blockOffs,
                                                  int* __restrict__ rowptr,
                                                  int* __restrict__ cursor,
                                                  float* __restrict__ dinv) {
    __shared__ int s[SCAN_T];
    const int t = threadIdx.x;
    const int i = blockIdx.x * SCAN_T + t;
    const int v = (i < NN) ? deg[i] : 0;
    s[t] = v;
    __syncthreads();
    for (int off = 1; off < SCAN_T; off <<= 1) {
        int u = (t >= off) ? s[t - off] : 0;
        int cur = s[t];
        __syncthreads();
        s[t] = cur + u;
        __syncthreads();
    }
    if (i < NN) {
        int ex = blockOffs[blockIdx.x] + s[t] - v;  // exclusive prefix
        rowptr[i] = ex;
        cursor[i] = ex;
        dinv[i] = rsqrtf((float)(v + 1));
    }
    if (i == 0) rowptr[NN] = NE;  // every edge's dst is in-range
}

// ---------------- scatter edges into CSR buckets ----------------
__global__ void k_scatter(const int* __restrict__ src, const int* __restrict__ dst,
                          int* __restrict__ cursor, int* __restrict__ csr_src) {
    int e = blockIdx.x * blockDim.x + threadIdx.x;
    if (e >= NE) return;
    int d = dst[e];
    int p = atomicAdd(&cursor[d], 1);
    csr_src[p] = src[e];
}

// ---------------- register-blocked GEMM, epilogue scales by dinv[row], writes bf16 ----------------
// Hb[row] = bf16( (X @ W)[row] * dinv[row] )
template <int CIN, int COUT, int RPT>
__global__ __launch_bounds__(256) void k_gemm(const float* __restrict__ X,
                                              const float* __restrict__ W,
                                              const float* __restrict__ dinv,
                                              ushort_t* __restrict__ Hb) {
    constexpr int TPR = COUT / 4;        // threads across cols
    constexpr int NGRP = 256 / TPR;      // row groups
    constexpr int BM = NGRP * RPT;       // rows per block
    constexpr int LDW = CIN + 4;         // LDS row stride (pad, keeps 16B align)
    constexpr int F4R = CIN / 4;
    __shared__ float xs[BM][LDW];
    const int tid = threadIdx.x;
    const int row0 = blockIdx.x * BM;

    for (int idx = tid; idx < BM * F4R; idx += 256) {
        int r = idx / F4R, c4 = idx % F4R;
        int row = row0 + r;
        float4 v = make_float4(0.f, 0.f, 0.f, 0.f);
        if (row < NN) v = ((const float4*)X)[(long)row * F4R + c4];
        *(float4*)&xs[r][c4 * 4] = v;
    }
    __syncthreads();

    const int g = tid / TPR;             // row group
    const int j = (tid % TPR) * 4;       // col
    const int r0 = g * RPT;

    float4 acc[RPT];
#pragma unroll
    for (int r = 0; r < RPT; ++r) acc[r] = make_float4(0.f, 0.f, 0.f, 0.f);

    for (int k = 0; k < CIN; k += 4) {
        const float4 w0 = *(const float4*)&W[(k + 0) * COUT + j];
        const float4 w1 = *(const float4*)&W[(k + 1) * COUT + j];
        const float4 w2 = *(const float4*)&W[(k + 2) * COUT + j];
        const float4 w3 = *(const float4*)&W[(k + 3) * COUT + j];
#pragma unroll
        for (int r = 0; r < RPT; ++r) {
            const float4 xv = *(const float4*)&xs[r0 + r][k];
            acc[r].x += xv.x * w0.x + xv.y * w1.x + xv.z * w2.x + xv.w * w3.x;
            acc[r].y += xv.x * w0.y + xv.y * w1.y + xv.z * w2.y + xv.w * w3.y;
            acc[r].z += xv.x * w0.z + xv.y * w1.z + xv.z * w2.z + xv.w * w3.z;
            acc[r].w += xv.x * w0.w + xv.y * w1.w + xv.z * w2.w + xv.w * w3.w;
        }
    }

#pragma unroll
    for (int r = 0; r < RPT; ++r) {
        int row = row0 + r0 + r;
        if (row < NN) {
            float sc = dinv[row];
            ushort4 o;
            o.x = f2bf(acc[r].x * sc);
            o.y = f2bf(acc[r].y * sc);
            o.z = f2bf(acc[r].z * sc);
            o.w = f2bf(acc[r].w * sc);
            *(ushort4*)&Hb[(long)row * COUT + j] = o;
        }
    }
}

// ---------------- gather aggregation on pre-scaled bf16 Hb ----------------
// OUT[d] = dd * (Hb[d] + sum_in Hb[s])  [+bias, relu]   (f32 accumulate)
template <int C, bool BIAS_RELU>
__global__ __launch_bounds__(256) void k_agg(const int* __restrict__ rowptr,
                                             const int* __restrict__ csr_src,
                                             const float* __restrict__ dinv,
                                             const ushort_t* __restrict__ Hb,
                                             const float* __restrict__ bias,
                                             float* __restrict__ OUT) {
    constexpr int TPN = C / 8;        // threads per node (uint4 = 8 bf16 channels)
    constexpr int NPB = 256 / TPN;    // nodes per block
    const int node = blockIdx.x * NPB + threadIdx.x / TPN;
    if (node >= NN) return;
    const int lane = threadIdx.x % TPN;
    const float dd = dinv[node];
    const uint4* __restrict__ H4 = (const uint4*)Hb;

    float a0, a1, a2, a3, a4, a5, a6, a7;
    {
        uint4 sv = H4[(long)node * TPN + lane];  // self term (pre-scaled)
        a0 = bf_lo(sv.x); a1 = bf_hi(sv.x);
        a2 = bf_lo(sv.y); a3 = bf_hi(sv.y);
        a4 = bf_lo(sv.z); a5 = bf_hi(sv.z);
        a6 = bf_lo(sv.w); a7 = bf_hi(sv.w);
    }

    const int beg = rowptr[node], end = rowptr[node + 1];
    int k = beg;
    const int n4 = beg + ((end - beg) & ~3);
    for (; k < n4; k += 4) {
        int s0 = csr_src[k + 0];
        int s1 = csr_src[k + 1];
        int s2 = csr_src[k + 2];
        int s3 = csr_src[k + 3];
        uint4 h0 = H4[(long)s0 * TPN + lane];
        uint4 h1 = H4[(long)s1 * TPN + lane];
        uint4 h2 = H4[(long)s2 * TPN + lane];
        uint4 h3 = H4[(long)s3 * TPN + lane];
        a0 += (bf_lo(h0.x) + bf_lo(h1.x)) + (bf_lo(h2.x) + bf_lo(h3.x));
        a1 += (bf_hi(h0.x) + bf_hi(h1.x)) + (bf_hi(h2.x) + bf_hi(h3.x));
        a2 += (bf_lo(h0.y) + bf_lo(h1.y)) + (bf_lo(h2.y) + bf_lo(h3.y));
        a3 += (bf_hi(h0.y) + bf_hi(h1.y)) + (bf_hi(h2.y) + bf_hi(h3.y));
        a4 += (bf_lo(h0.z) + bf_lo(h1.z)) + (bf_lo(h2.z) + bf_lo(h3.z));
        a5 += (bf_hi(h0.z) + bf_hi(h1.z)) + (bf_hi(h2.z) + bf_hi(h3.z));
        a6 += (bf_lo(h0.w) + bf_lo(h1.w)) + (bf_lo(h2.w) + bf_lo(h3.w));
        a7 += (bf_hi(h0.w) + bf_hi(h1.w)) + (bf_hi(h2.w) + bf_hi(h3.w));
    }
    for (; k < end; ++k) {
        int s = csr_src[k];
        uint4 h = H4[(long)s * TPN + lane];
        a0 += bf_lo(h.x); a1 += bf_hi(h.x);
        a2 += bf_lo(h.y); a3 += bf_hi(h.y);
        a4 += bf_lo(h.z); a5 += bf_hi(h.z);
        a6 += bf_lo(h.w); a7 += bf_hi(h.w);
    }

    a0 *= dd; a1 *= dd; a2 *= dd; a3 *= dd;
    a4 *= dd; a5 *= dd; a6 *= dd; a7 *= dd;
    if (BIAS_RELU) {
        const float4 b0 = *(const float4*)&bias[lane * 8];
        const float4 b1 = *(const float4*)&bias[lane * 8 + 4];
        a0 = fmaxf(a0 + b0.x, 0.f); a1 = fmaxf(a1 + b0.y, 0.f);
        a2 = fmaxf(a2 + b0.z, 0.f); a3 = fmaxf(a3 + b0.w, 0.f);
        a4 = fmaxf(a4 + b1.x, 0.f); a5 = fmaxf(a5 + b1.y, 0.f);
        a6 = fmaxf(a6 + b1.z, 0.f); a7 = fmaxf(a7 + b1.w, 0.f);
    }
    float* o = &OUT[(long)node * C + lane * 8];
    *(float4*)(o + 0) = make_float4(a0, a1, a2, a3);
    *(float4*)(o + 4) = make_float4(a4, a5, a6, a7);
}

// ---------------- two-stage per-graph mean pool (batch sorted) ----------------
__global__ __launch_bounds__(256) void k_pool1(const float* __restrict__ H,
                                               const int* __restrict__ batch,
                                               float* __restrict__ partial) {
    const int g = blockIdx.x / PSPLIT;
    const int s = blockIdx.x % PSPLIT;
    int beg, end;
    {
        int lo = 0, hi = NN;
        while (lo < hi) { int mid = (lo + hi) >> 1; if (batch[mid] < g) lo = mid + 1; else hi = mid; }
        beg = lo;
        lo = beg; hi = NN;
        while (lo < hi) { int mid = (lo + hi) >> 1; if (batch[mid] < g + 1) lo = mid + 1; else hi = mid; }
        end = lo;
    }
    const int c4 = threadIdx.x & 15;   // float4 channel group (64 ch = 16 float4)
    const int rg = threadIdx.x >> 4;   // 0..15 node subgroup
    const float4* __restrict__ H4 = (const float4*)H;

    float4 acc = make_float4(0.f, 0.f, 0.f, 0.f);
    for (int n = beg + s * 16 + rg; n < end; n += PSPLIT * 16) {
        float4 h = H4[(long)n * 16 + c4];
        acc.x += h.x; acc.y += h.y; acc.z += h.z; acc.w += h.w;
    }
    __shared__ float4 red[16][17];
    red[rg][c4] = acc;
    __syncthreads();
    if (rg == 0) {
        float4 t = red[0][c4];
#pragma unroll
        for (int i = 1; i < 16; ++i) {
            float4 u = red[i][c4];
            t.x += u.x; t.y += u.y; t.z += u.z; t.w += u.w;
        }
        ((float4*)partial)[(long)blockIdx.x * 16 + c4] = t;
    }
}

__global__ __launch_bounds__(64) void k_pool2(const float* __restrict__ partial,
                                              const int* __restrict__ batch,
                                              const float* __restrict__ b2,
                                              float* __restrict__ out) {
    const int g = blockIdx.x;
    const int ch = threadIdx.x;
    int beg, end;
    {
        int lo = 0, hi = NN;
        while (lo < hi) { int mid = (lo + hi) >> 1; if (batch[mid] < g) lo = mid + 1; else hi = mid; }
        beg = lo;
        lo = beg; hi = NN;
        while (lo < hi) { int mid = (lo + hi) >> 1; if (batch[mid] < g + 1) lo = mid + 1; else hi = mid; }
        end = lo;
    }
    float s = 0.f;
    for (int i = 0; i < PSPLIT; ++i) s += partial[(long)(g * PSPLIT + i) * 64 + ch];
    int cnt = end - beg;
    out[g * 64 + ch] = (cnt > 0) ? (s / (float)cnt + b2[ch]) : 0.f;
}

extern "C" void kernel_launch(void* const* d_in, const int* in_sizes, int n_in,
                              void* d_out, int out_size, void* d_ws, size_t ws_size,
                              hipStream_t stream) {
    const float* x  = (const float*)d_in[0];
    const float* W1 = (const float*)d_in[1];
    const float* b1 = (const float*)d_in[2];
    const float* W2 = (const float*)d_in[3];
    const float* b2 = (const float*)d_in[4];
    const int* ei   = (const int*)d_in[5];
    const int* src  = ei;
    const int* dst  = ei + NE;
    const int* batch = (const int*)d_in[6];
    float* out = (float*)d_out;

    char* p = (char*)d_ws;
    int* deg       = (int*)p;          p += (size_t)NN * 4;
    int* rowptr    = (int*)p;          p += (size_t)(NN + 4) * 4;
    int* cursor    = (int*)p;          p += (size_t)NN * 4;
    int* csr_src   = (int*)p;          p += (size_t)NE * 4;
    int* blockSums = (int*)p;          p += (size_t)64 * 4;
    int* blockOffs = (int*)p;          p += (size_t)64 * 4;
    float* dinv    = (float*)p;        p += (size_t)NN * 4;
    float* partial = (float*)p;        p += (size_t)NG * PSPLIT * 64 * 4;
    ushort_t* Hb   = (ushort_t*)p;     p += (size_t)NN * 128 * 2;   // bf16 GEMM output
    float* bufA    = (float*)p;        p += (size_t)NN * 128 * 4;   // f32 agg output (l1) / pool input (l2)
    float* bufB    = (float*)p;        p += (size_t)NN * 128 * 4;

    // ---- CSR build + normalization ----
    k_zero_deg<<<(NN + 255) / 256, 256, 0, stream>>>(deg);
    k_hist<<<(NE + 255) / 256, 256, 0, stream>>>(dst, deg);
    k_scan1<<<SCAN_NB, SCAN_T, 0, stream>>>(deg, blockSums);
    k_scan2<<<1, 64, 0, stream>>>(blockSums, blockOffs);
    k_scan3<<<SCAN_NB, SCAN_T, 0, stream>>>(deg, blockOffs, rowptr, cursor, dinv);
    k_scatter<<<(NE + 255) / 256, 256, 0, stream>>>(src, dst, cursor, csr_src);

    // ---- layer 1: C=128 -> 128 ----
    k_gemm<128, 128, 8><<<(NN + 63) / 64, 256, 0, stream>>>(x, W1, dinv, Hb);    // Hb = bf16((x@W1)*dinv)
    k_agg<128, true><<<(NN + 15) / 16, 256, 0, stream>>>(rowptr, csr_src, dinv, Hb, b1, bufB);

    // ---- layer 2: C=128 -> 64 ----
    k_gemm<128, 64, 4><<<(NN + 63) / 64, 256, 0, stream>>>(bufB, W2, dinv, Hb);  // Hb = bf16((h1@W2)*dinv)
    k_agg<64, false><<<(NN + 31) / 32, 256, 0, stream>>>(rowptr, csr_src, dinv, Hb, b2 /*unused*/, bufA);

    // ---- two-stage per-graph mean pool (+b2) ----
    k_pool1<<<NG * PSPLIT, 256, 0, stream>>>(bufA, batch, partial);
    k_pool2<<<NG, 64, 0, stream>>>(partial, batch, b2, out);
}